// Round 11
// baseline (114.626 us; speedup 1.0000x reference)
//
#include <hip/hip_runtime.h>

#define S 2048
#define D 128
#define BATCH 8
#define NS 4       // key-split factor (separate blocks, combined in k_comb)
#define KSTR 136   // K LDS row stride (halves)
#define VSTR 72    // V^T LDS row stride (halves)

typedef _Float16 half8 __attribute__((ext_vector_type(8)));
typedef _Float16 half4_t __attribute__((ext_vector_type(4)));
typedef float f4 __attribute__((ext_vector_type(4)));

__device__ __forceinline__ half8 cvt8(f4 a, f4 b) {
    half8 h;
    h[0] = (_Float16)a[0]; h[1] = (_Float16)a[1];
    h[2] = (_Float16)a[2]; h[3] = (_Float16)a[3];
    h[4] = (_Float16)b[0]; h[5] = (_Float16)b[1];
    h[6] = (_Float16)b[2]; h[7] = (_Float16)b[3];
    return h;
}

// ---- fused prep: K cast fp16, V transpose -> vt[b][d][t] fp16, per-chunk V
// colsum partials (plain stores, no atomics, no memset). 1024 blocks x 16 rows
// = 4 blocks/CU; b = bid & 7 keeps batch->XCD affinity (1024 % 8 == 0).
__global__ __launch_bounds__(256) void k_prep(const float* __restrict__ kin,
                                              const float* __restrict__ v,
                                              _Float16* __restrict__ kh,
                                              _Float16* __restrict__ vt,
                                              float* __restrict__ vpart) {
    int bid = blockIdx.x;
    int b = bid & 7, c = bid >> 3, tid = threadIdx.x;   // c: 0..127, 16 rows each
    size_t off = ((size_t)b * S + c * 16) * D;
    {   // K cast: 16*128 = 2048 floats = 256 threads x 8
        size_t i = (size_t)tid * 8;
        f4 a = *(const f4*)(kin + off + i);
        f4 bb = *(const f4*)(kin + off + i + 4);
        *(half8*)(kh + off + i) = cvt8(a, bb);
    }
    __shared__ float tile[16 * 132];
    __shared__ f4 sred[256][2];
    int d0 = (tid & 15) * 8, t = tid >> 4;
    f4 x = *(const f4*)(v + off + (size_t)t * D + d0);
    f4 y = *(const f4*)(v + off + (size_t)t * D + d0 + 4);
    *(f4*)&tile[t * 132 + d0] = x;
    *(f4*)&tile[t * 132 + d0 + 4] = y;
    sred[tid][0] = x; sred[tid][1] = y;
    __syncthreads();
    if (tid < 16) {     // per-chunk partial colsum over this chunk's 16 rows
        f4 s0 = sred[tid][0], s1 = sred[tid][1];
        for (int g = 1; g < 16; ++g) { s0 += sred[g * 16 + tid][0]; s1 += sred[g * 16 + tid][1]; }
        float* dst = vpart + ((size_t)b * 128 + c) * 128 + tid * 8;
        *(f4*)dst = s0;
        *(f4*)(dst + 4) = s1;
    }
    int u = tid & 1, dd = tid >> 1;                    // dd: 0..127, u: 2 row-halves
    half8 h;
    #pragma unroll
    for (int i2 = 0; i2 < 8; ++i2) h[i2] = (_Float16)tile[(u * 8 + i2) * 132 + dd];
    *(half8*)(vt + ((size_t)(b * D + dd)) * S + c * 16 + u * 8) = h;
}

// ---- main: flash attention, NS=4 key-split across SEPARATE 256-thread
// blocks (proven R9 structure: chain <= 8 steps, 4 blocks/CU co-resident,
// concurrent blocks overlap latency; 60 VGPR measured). Static mapping
// b = bid&7 (XCD L2 affinity with prep), mg = (bid>>3)&31, j = bid>>8.
// Blocks with j >= nkt write ZERO partials so k_comb sums unconditionally.
__global__ __launch_bounds__(256, 4) void k_attn(
    const float* __restrict__ q, const _Float16* __restrict__ kh,
    const _Float16* __restrict__ vt, const int* __restrict__ el,
    _Float16* __restrict__ part, float* __restrict__ stats) {
    int bid = blockIdx.x;
    int b = bid & 7, mg = (bid >> 3) & 31, j = bid >> 8;
    int Lb = el[b], m0 = mg * 64;
    if (m0 >= Lb) return;              // k_comb handles these rows (colmean)
    int nkt = (Lb + 63) >> 6;

    int tid = threadIdx.x, lane = tid & 63, w = tid >> 6;
    int col = lane & 15, quad = lane >> 4;

    __shared__ _Float16 Kh[64 * KSTR];
    __shared__ _Float16 Vt[128 * VSTR];

    // Q frags (B-operand of the S^T MFMA), fp32 -> fp16 with 1/sqrt(D)
    const float scale = 0.0883883476483184f;
    half8 qf[4];
    {
        const float* qb = q + ((size_t)b * S + m0 + w * 16 + col) * D;
        #pragma unroll
        for (int kc = 0; kc < 4; ++kc) {
            f4 a = *(const f4*)(qb + kc * 32 + quad * 8);
            f4 b2 = *(const f4*)(qb + kc * 32 + quad * 8 + 4);
            a *= scale; b2 *= scale;
            qf[kc] = cvt8(a, b2);
        }
    }

    f4 O[8];
    #pragma unroll
    for (int i = 0; i < 8; ++i) O[i] = (f4){0.f, 0.f, 0.f, 0.f};
    float ps = 0.f;

    int kr = tid >> 4, kc8 = (tid & 15) << 3;
    int vr = tid >> 3, vc8 = (tid & 7) << 3;
    const _Float16* kb_ = kh + (size_t)b * S * D;
    const _Float16* vb_ = vt + (size_t)b * D * S;

    if (j < nkt) {
        half8 kreg[4], vreg[4];
        {   // stage tile j
            int t0 = j * 64;
            #pragma unroll
            for (int p = 0; p < 4; ++p)
                kreg[p] = *(const half8*)(kb_ + (size_t)(t0 + p * 16 + kr) * D + kc8);
            #pragma unroll
            for (int p = 0; p < 4; ++p)
                vreg[p] = *(const half8*)(vb_ + (size_t)(p * 32 + vr) * S + t0 + vc8);
            #pragma unroll
            for (int p = 0; p < 4; ++p)
                *(half8*)&Kh[(p * 16 + kr) * KSTR + kc8] = kreg[p];
            #pragma unroll
            for (int p = 0; p < 4; ++p)
                *(half8*)&Vt[(p * 32 + vr) * VSTR + vc8] = vreg[p];
        }
        __syncthreads();

        for (int kt = j; kt < nkt; kt += NS) {
            int t0 = kt * 64;
            bool hasnext = (kt + NS) < nkt;
            if (hasnext) {  // prefetch next tile into regs, overlaps compute
                int tn = t0 + NS * 64;
                #pragma unroll
                for (int p = 0; p < 4; ++p)
                    kreg[p] = *(const half8*)(kb_ + (size_t)(tn + p * 16 + kr) * D + kc8);
                #pragma unroll
                for (int p = 0; p < 4; ++p)
                    vreg[p] = *(const half8*)(vb_ + (size_t)(p * 32 + vr) * S + tn + vc8);
            }

            #pragma unroll
            for (int nt = 0; nt < 4; ++nt) {
                // S^T = K Q^T: C[key = nt*16 + quad*4 + r][qrow = col]
                f4 sa = {0.f, 0.f, 0.f, 0.f};
                __builtin_amdgcn_s_setprio(1);
                #pragma unroll
                for (int kc = 0; kc < 4; ++kc) {
                    half8 kf = *(const half8*)&Kh[(nt * 16 + col) * KSTR + kc * 32 + quad * 8];
                    sa = __builtin_amdgcn_mfma_f32_16x16x32_f16(kf, qf[kc], sa, 0, 0, 0);
                }
                __builtin_amdgcn_s_setprio(0);
                // exp with key-validity mask; P = A-frag of 16x16x16 (k=quad*4+r)
                int tq = t0 + nt * 16 + quad * 4;
                half4_t ph;
                #pragma unroll
                for (int r = 0; r < 4; ++r) {
                    float e = (tq + r < Lb) ? __expf(fminf(sa[r], 10.0f)) : 0.f;
                    ps += e;
                    ph[r] = (_Float16)e;
                }
                // O += P V for this 16-key group
                __builtin_amdgcn_s_setprio(1);
                #pragma unroll
                for (int dt = 0; dt < 8; ++dt) {
                    half4_t vf = *(const half4_t*)&Vt[(dt * 16 + col) * VSTR + nt * 16 + quad * 4];
                    O[dt] = __builtin_amdgcn_mfma_f32_16x16x16f16(ph, vf, O[dt], 0, 0, 0);
                }
                __builtin_amdgcn_s_setprio(0);
            }

            if (hasnext) {
                __syncthreads();
                #pragma unroll
                for (int p = 0; p < 4; ++p)
                    *(half8*)&Kh[(p * 16 + kr) * KSTR + kc8] = kreg[p];
                #pragma unroll
                for (int p = 0; p < 4; ++p)
                    *(half8*)&Vt[(p * 32 + vr) * VSTR + vc8] = vreg[p];
                __syncthreads();
            }
        }
    }

    // epilogue: reduce l over quads (2 shfls), write fp16 partials + stats.
    // Unconditional: j >= nkt blocks write zeros (k_comb sums all NS splits).
    ps += __shfl_xor(ps, 16, 64);
    ps += __shfl_xor(ps, 32, 64);
    size_t pbase = (size_t)(j * BATCH + b) * S;
    #pragma unroll
    for (int dt = 0; dt < 8; ++dt)
        #pragma unroll
        for (int r = 0; r < 4; ++r) {
            int row = m0 + w * 16 + quad * 4 + r;
            part[(pbase + row) * D + dt * 16 + col] = (_Float16)O[dt][r];
        }
    if (quad == 0) stats[pbase + m0 + w * 16 + col] = ps;
}

// ---- combine: sum NS splits, normalize; rows >= L get colmean(V) from the
// prep partials. 1024 blocks x 16 rows = 4 blocks/CU (TLP), b = bid&7 keeps
// part/stats reads XCD-L2-local with k_attn's writes.
__global__ __launch_bounds__(256, 4) void k_comb(
    const _Float16* __restrict__ part, const float* __restrict__ stats,
    const float* __restrict__ vpart, const int* __restrict__ el,
    float* __restrict__ out) {
    int bid = blockIdx.x;
    int b = bid & 7, mg16 = bid >> 3;              // 0..127, 16 rows each
    int L = el[b], m0 = mg16 * 16, tid = threadIdx.x;
    const float inv_s = 1.0f / (float)S;
    __shared__ float vsum[128];

    bool tail = (m0 + 16 > L);         // block-uniform
    if (tail) {                        // colmean(V) = reduce 128 prep partials
        if (tid < 128) {
            float s = 0.f;
            const float* pp = vpart + (size_t)b * 128 * 128 + tid;
            #pragma unroll 4
            for (int c = 0; c < 128; ++c) s += pp[c * 128];
            vsum[tid] = s * inv_s;
        }
        __syncthreads();
    }

    int r = tid >> 4, d08 = (tid & 15) * 8;        // 16 rows x 16 col-slots
    int srow = m0 + r;
    float* orow = out + ((size_t)b * S + srow) * D + d08;
    if (srow >= L) {
        *(f4*)orow = *(const f4*)(vsum + d08);
        *(f4*)(orow + 4) = *(const f4*)(vsum + d08 + 4);
        return;
    }
    size_t rbase = (size_t)b * S + srow;
    const size_t step = (size_t)BATCH * S;
    float l = 0.f;
    #pragma unroll
    for (int jj = 0; jj < NS; ++jj) l += stats[rbase + jj * step];
    float inv = 1.0f / l;
    f4 o0 = {0.f, 0.f, 0.f, 0.f}, o1 = {0.f, 0.f, 0.f, 0.f};
    #pragma unroll
    for (int jj = 0; jj < NS; ++jj) {
        half8 h = *(const half8*)(part + (rbase + jj * step) * D + d08);
        f4 x0 = {(float)h[0], (float)h[1], (float)h[2], (float)h[3]};
        f4 x1 = {(float)h[4], (float)h[5], (float)h[6], (float)h[7]};
        o0 += x0; o1 += x1;
    }
    *(f4*)orow = o0 * inv;
    *(f4*)(orow + 4) = o1 * inv;
}

extern "C" void kernel_launch(void* const* d_in, const int* in_sizes, int n_in,
                              void* d_out, int out_size, void* d_ws, size_t ws_size,
                              hipStream_t stream) {
    const float* q = (const float*)d_in[0];
    const float* k = (const float*)d_in[1];
    const float* v = (const float*)d_in[2];
    const int* el = (const int*)d_in[3];
    float* out = (float*)d_out;

    const size_t SZ_VPART = (size_t)BATCH * 128 * 128 * 4;    // 512 KB
    const size_t SZ_HALF  = (size_t)BATCH * D * S * 2;        // 4.19 MB each
    const size_t SZ_STAT  = (size_t)NS * BATCH * S * 4;       // 256 KB
    float* vpart = (float*)d_ws;
    _Float16* kh = (_Float16*)((char*)d_ws + SZ_VPART);
    _Float16* vt = (_Float16*)((char*)d_ws + SZ_VPART + SZ_HALF);
    float* stats = (float*)((char*)d_ws + SZ_VPART + 2 * SZ_HALF);
    _Float16* part = (_Float16*)((char*)d_ws + SZ_VPART + 2 * SZ_HALF + SZ_STAT);

    k_prep<<<dim3(1024), 256, 0, stream>>>(k, v, kh, vt, vpart);
    k_attn<<<dim3(1024), 256, 0, stream>>>(q, kh, vt, el, part, stats);
    k_comb<<<dim3(1024), 256, 0, stream>>>(part, stats, vpart, el, out);
}

// Round 13
// 106.855 us; speedup vs baseline: 1.0727x; 1.0727x over previous
//
#include <hip/hip_runtime.h>

#define S 2048
#define D 128
#define BATCH 8
#define NS 4       // key-split factor (separate blocks, combined in k_comb)
#define KSTR 136   // K LDS row stride (halves)
#define VSTR 72    // V^T LDS row stride (halves)
#define NATT 1024  // attention blocks; bid >= NATT are V-colsum blocks

typedef _Float16 half8 __attribute__((ext_vector_type(8)));
typedef _Float16 half4_t __attribute__((ext_vector_type(4)));
typedef float f4 __attribute__((ext_vector_type(4)));

__device__ __forceinline__ half8 cvt8(f4 a, f4 b) {
    half8 h;
    h[0] = (_Float16)a[0]; h[1] = (_Float16)a[1];
    h[2] = (_Float16)a[2]; h[3] = (_Float16)a[3];
    h[4] = (_Float16)b[0]; h[5] = (_Float16)b[1];
    h[6] = (_Float16)b[2]; h[7] = (_Float16)b[3];
    return h;
}

// ---- main: flash attention with NO prep kernel. NS=4 key-split across
// separate 256-thread blocks (proven R9 structure: chain <= 8 steps,
// 4 blocks/CU). LDS = Kh 17408 + Vt 18432 = 35840 B (4 blocks/CU -> 143 KB
// of 160, OK). K staged directly from fp32 with in-register cast; V staged
// TRANSPOSED from fp32 row-major via per-thread d-column ownership
// (wave-coalesced dword loads; proven Vt[d][t] read path untouched).
// bid >= NATT blocks compute V colsum partials for k_comb's fallback rows.
__global__ __launch_bounds__(256, 4) void k_attn(
    const float* __restrict__ q, const float* __restrict__ kin,
    const float* __restrict__ v, const int* __restrict__ el,
    _Float16* __restrict__ part, float* __restrict__ stats,
    float* __restrict__ vpart) {
    int bid = blockIdx.x, tid = threadIdx.x;

    __shared__ __align__(16) char smem[35840];   // Kh 17408 + Vt 18432

    if (bid >= NATT) {
        // ---- V colsum partials: 32 blocks, (b, seg) sums 512 rows x 128 d
        int cs = bid - NATT;
        int b = cs & 7, seg = cs >> 3;           // seg: 0..3
        f4 a0 = {0.f, 0.f, 0.f, 0.f}, a1 = {0.f, 0.f, 0.f, 0.f};
        int d0 = (tid & 15) * 8, tl = tid >> 4;
        const float* vb = v + ((size_t)b * S + seg * 512) * D;
        #pragma unroll 4
        for (int it = 0; it < 32; ++it) {
            const float* row = vb + (size_t)(it * 16 + tl) * D + d0;
            a0 += *(const f4*)row;
            a1 += *(const f4*)(row + 4);
        }
        f4 (*sred)[2] = (f4 (*)[2])smem;         // 256 x 32 B = 8 KB
        sred[tid][0] = a0; sred[tid][1] = a1;
        __syncthreads();
        if (tid < 16) {
            f4 s0 = sred[tid][0], s1 = sred[tid][1];
            for (int g = 1; g < 16; ++g) { s0 += sred[g * 16 + tid][0]; s1 += sred[g * 16 + tid][1]; }
            float* dst = vpart + ((size_t)b * 4 + seg) * 128 + tid * 8;
            *(f4*)dst = s0;
            *(f4*)(dst + 4) = s1;
        }
        return;
    }

    int b = bid & 7, mg = (bid >> 3) & 31, j = bid >> 8;
    int Lb = el[b], m0 = mg * 64;
    if (m0 >= Lb) return;              // k_comb handles these rows (colmean)
    int nkt = (Lb + 63) >> 6;

    int lane = tid & 63, w = tid >> 6;
    int col = lane & 15, quad = lane >> 4;

    _Float16* Kh = (_Float16*)smem;               // 64*136*2 = 17408 B
    _Float16* Vt = (_Float16*)(smem + 17408);     // 128*72*2 = 18432 B

    // Q frags (B-operand of the S^T MFMA), fp32 -> fp16 with 1/sqrt(D)
    const float scale = 0.0883883476483184f;
    half8 qf[4];
    {
        const float* qb = q + ((size_t)b * S + m0 + w * 16 + col) * D;
        #pragma unroll
        for (int kc = 0; kc < 4; ++kc) {
            f4 a = *(const f4*)(qb + kc * 32 + quad * 8);
            f4 b2 = *(const f4*)(qb + kc * 32 + quad * 8 + 4);
            a *= scale; b2 *= scale;
            qf[kc] = cvt8(a, b2);
        }
    }

    f4 O[8];
    #pragma unroll
    for (int i = 0; i < 8; ++i) O[i] = (f4){0.f, 0.f, 0.f, 0.f};
    float ps = 0.f;

    int kr = tid >> 4, kc8 = (tid & 15) << 3;   // K stage: 4 rows/thread
    int dv = tid & 127, oct = tid >> 7;         // V stage: 1 d-col, 4 t-octets
    const float* kb_ = kin + (size_t)b * S * D;
    const float* vb_ = v + (size_t)b * S * D;

    half8 kreg[4], vreg[4];
    if (j < nkt) {
        {   // stage tile j (fp32 -> fp16 in-register)
            int t0 = j * 64;
            #pragma unroll
            for (int p = 0; p < 4; ++p) {
                const float* kp = kb_ + (size_t)(t0 + p * 16 + kr) * D + kc8;
                kreg[p] = cvt8(*(const f4*)kp, *(const f4*)(kp + 4));
            }
            #pragma unroll
            for (int p = 0; p < 4; ++p) {
                int o = p * 2 + oct;
                const float* vp = vb_ + (size_t)(t0 + o * 8) * D + dv;
                half8 h;
                #pragma unroll
                for (int i = 0; i < 8; ++i) h[i] = (_Float16)vp[(size_t)i * D];
                vreg[p] = h;
            }
            #pragma unroll
            for (int p = 0; p < 4; ++p)
                *(half8*)&Kh[(p * 16 + kr) * KSTR + kc8] = kreg[p];
            #pragma unroll
            for (int p = 0; p < 4; ++p) {
                int o = p * 2 + oct;
                *(half8*)&Vt[dv * VSTR + o * 8] = vreg[p];
            }
        }
        __syncthreads();

        for (int kt = j; kt < nkt; kt += NS) {
            int t0 = kt * 64;
            bool hasnext = (kt + NS) < nkt;
            if (hasnext) {  // prefetch next tile into regs, overlaps compute
                int tn = t0 + NS * 64;
                #pragma unroll
                for (int p = 0; p < 4; ++p) {
                    const float* kp = kb_ + (size_t)(tn + p * 16 + kr) * D + kc8;
                    kreg[p] = cvt8(*(const f4*)kp, *(const f4*)(kp + 4));
                }
                #pragma unroll
                for (int p = 0; p < 4; ++p) {
                    int o = p * 2 + oct;
                    const float* vp = vb_ + (size_t)(tn + o * 8) * D + dv;
                    half8 h;
                    #pragma unroll
                    for (int i = 0; i < 8; ++i) h[i] = (_Float16)vp[(size_t)i * D];
                    vreg[p] = h;
                }
            }

            #pragma unroll
            for (int nt = 0; nt < 4; ++nt) {
                // S^T = K Q^T: C[key = nt*16 + quad*4 + r][qrow = col]
                f4 sa = {0.f, 0.f, 0.f, 0.f};
                __builtin_amdgcn_s_setprio(1);
                #pragma unroll
                for (int kc = 0; kc < 4; ++kc) {
                    half8 kf = *(const half8*)&Kh[(nt * 16 + col) * KSTR + kc * 32 + quad * 8];
                    sa = __builtin_amdgcn_mfma_f32_16x16x32_f16(kf, qf[kc], sa, 0, 0, 0);
                }
                __builtin_amdgcn_s_setprio(0);
                // exp with key-validity mask; P = A-frag of 16x16x16 (k=quad*4+r)
                int tq = t0 + nt * 16 + quad * 4;
                half4_t ph;
                #pragma unroll
                for (int r = 0; r < 4; ++r) {
                    float e = (tq + r < Lb) ? __expf(fminf(sa[r], 10.0f)) : 0.f;
                    ps += e;
                    ph[r] = (_Float16)e;
                }
                // O += P V for this 16-key group
                __builtin_amdgcn_s_setprio(1);
                #pragma unroll
                for (int dt = 0; dt < 8; ++dt) {
                    half4_t vf = *(const half4_t*)&Vt[(dt * 16 + col) * VSTR + nt * 16 + quad * 4];
                    O[dt] = __builtin_amdgcn_mfma_f32_16x16x16f16(ph, vf, O[dt], 0, 0, 0);
                }
                __builtin_amdgcn_s_setprio(0);
            }

            if (hasnext) {
                __syncthreads();
                #pragma unroll
                for (int p = 0; p < 4; ++p)
                    *(half8*)&Kh[(p * 16 + kr) * KSTR + kc8] = kreg[p];
                #pragma unroll
                for (int p = 0; p < 4; ++p) {
                    int o = p * 2 + oct;
                    *(half8*)&Vt[dv * VSTR + o * 8] = vreg[p];
                }
                __syncthreads();
            }
        }
    }

    // epilogue: reduce l over quads (2 shfls), write fp16 partials + stats.
    // Unconditional: j >= nkt blocks write zeros (k_comb sums all NS splits).
    ps += __shfl_xor(ps, 16, 64);
    ps += __shfl_xor(ps, 32, 64);
    size_t pbase = (size_t)(j * BATCH + b) * S;
    #pragma unroll
    for (int dt = 0; dt < 8; ++dt)
        #pragma unroll
        for (int r = 0; r < 4; ++r) {
            int row = m0 + w * 16 + quad * 4 + r;
            part[(pbase + row) * D + dt * 16 + col] = (_Float16)O[dt][r];
        }
    if (quad == 0) stats[pbase + m0 + w * 16 + col] = ps;
}

// ---- combine: sum NS splits, normalize; rows >= L get colmean(V) from the
// 4-segment colsum partials. 1024 blocks x 16 rows, b = bid&7 XCD-affine.
__global__ __launch_bounds__(256, 4) void k_comb(
    const _Float16* __restrict__ part, const float* __restrict__ stats,
    const float* __restrict__ vpart, const int* __restrict__ el,
    float* __restrict__ out) {
    int bid = blockIdx.x;
    int b = bid & 7, mg16 = bid >> 3;              // 0..127, 16 rows each
    int L = el[b], m0 = mg16 * 16, tid = threadIdx.x;
    const float inv_s = 1.0f / (float)S;
    __shared__ float vsum[128];

    bool tail = (m0 + 16 > L);         // block-uniform
    if (tail) {                        // colmean(V) = reduce 4 segment partials
        if (tid < 128) {
            const float* pp = vpart + (size_t)b * 4 * 128 + tid;
            float s = pp[0] + pp[128] + pp[256] + pp[384];
            vsum[tid] = s * inv_s;
        }
        __syncthreads();
    }

    int r = tid >> 4, d08 = (tid & 15) * 8;        // 16 rows x 16 col-slots
    int srow = m0 + r;
    float* orow = out + ((size_t)b * S + srow) * D + d08;
    if (srow >= L) {
        *(f4*)orow = *(const f4*)(vsum + d08);
        *(f4*)(orow + 4) = *(const f4*)(vsum + d08 + 4);
        return;
    }
    size_t rbase = (size_t)b * S + srow;
    const size_t step = (size_t)BATCH * S;
    float l = 0.f;
    #pragma unroll
    for (int jj = 0; jj < NS; ++jj) l += stats[rbase + jj * step];
    float inv = 1.0f / l;
    f4 o0 = {0.f, 0.f, 0.f, 0.f}, o1 = {0.f, 0.f, 0.f, 0.f};
    #pragma unroll
    for (int jj = 0; jj < NS; ++jj) {
        half8 h = *(const half8*)(part + (rbase + jj * step) * D + d08);
        f4 x0 = {(float)h[0], (float)h[1], (float)h[2], (float)h[3]};
        f4 x1 = {(float)h[4], (float)h[5], (float)h[6], (float)h[7]};
        o0 += x0; o1 += x1;
    }
    *(f4*)orow = o0 * inv;
    *(f4*)(orow + 4) = o1 * inv;
}

extern "C" void kernel_launch(void* const* d_in, const int* in_sizes, int n_in,
                              void* d_out, int out_size, void* d_ws, size_t ws_size,
                              hipStream_t stream) {
    const float* q = (const float*)d_in[0];
    const float* k = (const float*)d_in[1];
    const float* v = (const float*)d_in[2];
    const int* el = (const int*)d_in[3];
    float* out = (float*)d_out;

    const size_t SZ_VPART = (size_t)BATCH * 4 * 128 * 4;      // 16 KB
    const size_t SZ_STAT  = (size_t)NS * BATCH * S * 4;       // 256 KB
    float* vpart = (float*)d_ws;
    float* stats = (float*)((char*)d_ws + SZ_VPART);
    _Float16* part = (_Float16*)((char*)d_ws + SZ_VPART + SZ_STAT);

    k_attn<<<dim3(NATT + 32), 256, 0, stream>>>(q, k, v, el, part, stats, vpart);
    k_comb<<<dim3(1024), 256, 0, stream>>>(part, stats, vpart, el, out);
}